// Round 9
// baseline (139.701 us; speedup 1.0000x reference)
//
#include <hip/hip_runtime.h>
#include <cstdint>
#include <cstddef>

#define GNPB 8        // blkoff granularity (edge offset every 8 nodes)
#define MNPB 16       // rows per fused block (= gemm tile rows)
#define GAST 264      // LDS A row stride in elems (528 B) — breaks 512B-stride banks
#define DFRNG 512     // nodes scanned per repair block
#define VP_BLOCKS 16  // prep blocks packing Vp (4096 threads, K=256)
#define VPG_BLOCKS 8  // prep blocks packing Vpg (2048 threads, K=128, Wg only)

typedef __attribute__((ext_vector_type(8))) short bf16x8;
typedef __attribute__((ext_vector_type(4))) float f32x4;

static __device__ __forceinline__ unsigned short f2bf(float f) {
    unsigned int u = __builtin_bit_cast(unsigned int, f);
    u += 0x7fffu + ((u >> 16) & 1u);
    return (unsigned short)(u >> 16);
}
static __device__ __forceinline__ float bfhi(unsigned int u) { return __builtin_bit_cast(float, u & 0xFFFF0000u); }
static __device__ __forceinline__ float bflo(unsigned int u) { return __builtin_bit_cast(float, u << 16); }
// masked bf16x8 accumulate: m = all-ones keeps, 0 zeroes (bf16 0x0000 == +0.0)
static __device__ __forceinline__ void acc8(float* a, const uint4& v, unsigned m) {
    unsigned x0 = v.x & m, x1 = v.y & m, x2 = v.z & m, x3 = v.w & m;
    a[0] += bflo(x0); a[1] += bfhi(x0); a[2] += bflo(x1); a[3] += bfhi(x1);
    a[4] += bflo(x2); a[5] += bfhi(x2); a[6] += bflo(x3); a[7] += bfhi(x3);
}

// ---------------- Prep: Vp/Vpg pack, xb = bf16(x), blkoff ----------------
// Vp layout: element ((g*8 + s)*64 + lane)*8 + j = B1[g*16 + (lane&15)][s*32 + (lane>>4)*8 + j]
// (B1 = [Wg+Ws | Wl], K=256). Vpg: same pattern, 4 k-steps, Wg only (K=128).
__global__ __launch_bounds__(256)
void prep(const float* __restrict__ x, const float* __restrict__ Wg,
          const float* __restrict__ Wl, const float* __restrict__ Ws,
          const int* __restrict__ dst,
          unsigned short* __restrict__ Vp, unsigned short* __restrict__ Vpg,
          unsigned short* __restrict__ xb, int* __restrict__ blkoff,
          int total8, int nblk_g, int noffb, int E) {
    const int bx = blockIdx.x, t = threadIdx.x;
    if (bx < VP_BLOCKS) {
        int gid = bx * 256 + t;
        if (gid < 4096) {
            int l = gid & 63, srow = (gid >> 6) & 7, g = gid >> 9;
            int o = g * 16 + (l & 15);
            int k = srow * 32 + (l >> 4) * 8;
            uint4 u;
            if (k < 128) {                     // first K-segment: W1 = Wg + Ws
                const float* pg = Wg + o * 128 + k;
                const float* ps = Ws + o * 128 + k;
                u.x = (unsigned)f2bf(pg[0]+ps[0]) | ((unsigned)f2bf(pg[1]+ps[1]) << 16);
                u.y = (unsigned)f2bf(pg[2]+ps[2]) | ((unsigned)f2bf(pg[3]+ps[3]) << 16);
                u.z = (unsigned)f2bf(pg[4]+ps[4]) | ((unsigned)f2bf(pg[5]+ps[5]) << 16);
                u.w = (unsigned)f2bf(pg[6]+ps[6]) | ((unsigned)f2bf(pg[7]+ps[7]) << 16);
            } else {                           // second K-segment: Wl
                const float* pl = Wl + o * 128 + (k - 128);
                u.x = (unsigned)f2bf(pl[0]) | ((unsigned)f2bf(pl[1]) << 16);
                u.y = (unsigned)f2bf(pl[2]) | ((unsigned)f2bf(pl[3]) << 16);
                u.z = (unsigned)f2bf(pl[4]) | ((unsigned)f2bf(pl[5]) << 16);
                u.w = (unsigned)f2bf(pl[6]) | ((unsigned)f2bf(pl[7]) << 16);
            }
            ((uint4*)Vp)[gid] = u;
        }
    } else if (bx < VP_BLOCKS + VPG_BLOCKS) {
        int gid = (bx - VP_BLOCKS) * 256 + t;  // 2048 entries: Wg-only panel, K=128
        if (gid < 2048) {
            int l = gid & 63, s = (gid >> 6) & 3, g = gid >> 8;
            int o = g * 16 + (l & 15);
            int k = s * 32 + (l >> 4) * 8;
            const float* p = Wg + o * 128 + k;
            uint4 u;
            u.x = (unsigned)f2bf(p[0]) | ((unsigned)f2bf(p[1]) << 16);
            u.y = (unsigned)f2bf(p[2]) | ((unsigned)f2bf(p[3]) << 16);
            u.z = (unsigned)f2bf(p[4]) | ((unsigned)f2bf(p[5]) << 16);
            u.w = (unsigned)f2bf(p[6]) | ((unsigned)f2bf(p[7]) << 16);
            ((uint4*)Vpg)[gid] = u;
        }
    } else if (bx < VP_BLOCKS + VPG_BLOCKS + noffb) {
        int b = (bx - VP_BLOCKS - VPG_BLOCKS) * 256 + t;
        if (b < nblk_g) {
            int target = b * GNPB;
            int lo = 0, hi = E;
            while (lo < hi) { int mid = (lo + hi) >> 1; if (dst[mid] < target) lo = mid + 1; else hi = mid; }
            blkoff[b] = lo;
        }
    } else {
        int gid = (bx - VP_BLOCKS - VPG_BLOCKS - noffb) * 256 + t;
        if (gid < total8) {
            const float4* px = (const float4*)x + (size_t)gid * 2;
            float4 a = px[0], bq = px[1];
            uint4 u;
            u.x = (unsigned)f2bf(a.x)  | ((unsigned)f2bf(a.y)  << 16);
            u.y = (unsigned)f2bf(a.z)  | ((unsigned)f2bf(a.w)  << 16);
            u.z = (unsigned)f2bf(bq.x) | ((unsigned)f2bf(bq.y) << 16);
            u.w = (unsigned)f2bf(bq.z) | ((unsigned)f2bf(bq.w) << 16);
            ((uint4*)xb)[gid] = u;
        }
    }
}

// ---------------- Fused gather + GEMM + repair (one dispatch) ----------------
// 512 threads / 8 waves / 16 nodes per block. Gather: 2 nodes per wave SEQUENTIALLY,
// each via the proven 1-node-per-wave body (depth-2 chains — R1's failure was depth-4
// with only 4 waves); means written straight into the LDS A-panel (no Mm round-trip).
// GEMM: one col-group per wave (8 waves x 16 cols), 8 MFMA/wave, B streamed from Vp.
// deg==0 rows skipped in the epilogue (in-register shfl mask); trailing repair blocks
// own them: scan 512-node range, compact to LDS, K=128 MFMA vs Vpg.
__global__ __launch_bounds__(512, 5)
void ggemm(const unsigned short* __restrict__ xb, const int* __restrict__ src,
           const int* __restrict__ deg, const int* __restrict__ blkoff,
           const unsigned short* __restrict__ Vp, const unsigned short* __restrict__ Vpg,
           const float* __restrict__ bias, float* __restrict__ out, int N, int ngemm) {
    __shared__ __align__(16) unsigned short As[MNPB * GAST];
    const int t = threadIdx.x, wv = t >> 6, lane = t & 63;
    const int c = lane & 15, p = lane >> 4;          // p doubles as the C/D quad index

    if (blockIdx.x >= ngemm) {
        // ---------- repair path ----------
        __shared__ int nds[DFRNG];
        __shared__ int ncnt;
        const int rb = (blockIdx.x - ngemm) * DFRNG;
        if (t == 0) ncnt = 0;
        __syncthreads();
        {
            int n = rb + t;
            if (n < N && deg[n] == 0) nds[atomicAdd(&ncnt, 1)] = n;
        }
        __syncthreads();
        const int cnt = ncnt;
        if (cnt == 0) return;
        const bf16x8* VB = (const bf16x8*)Vpg;
        const int col = wv * 16 + c;
        const float bv = bias[col];
        for (int base = 0; base < cnt; base += 16) {
            if (t < 256) {                            // stage 16 compacted rows
                int row = t >> 4, ch = t & 15;
                int i = base + row; if (i > cnt - 1) i = cnt - 1;
                int node = nds[i];
                *(uint4*)(As + row * GAST + ch * 8) =
                    *(const uint4*)(xb + (size_t)node * 128 + ch * 8);
            }
            bf16x8 b0 = VB[(wv * 4) * 64 + lane];
            __syncthreads();
            f32x4 acc = (f32x4){0.f, 0.f, 0.f, 0.f};
#pragma unroll
            for (int s2 = 0; s2 < 4; ++s2) {
                int sn = (s2 + 1) & 3;
                bf16x8 n0 = VB[(wv * 4 + sn) * 64 + lane];
                bf16x8 a0 = *(const bf16x8*)(As + c * GAST + s2 * 32 + p * 8);
                acc = __builtin_amdgcn_mfma_f32_16x16x32_bf16(a0, b0, acc, 0, 0, 0);
                b0 = n0;
            }
#pragma unroll
            for (int reg = 0; reg < 4; ++reg) {
                int i = base + p * 4 + reg;
                if (i < cnt) {
                    int n = nds[i];
                    float v = acc[reg] + bv;
                    out[(size_t)n * 128 + col] = (v > 0.f) ? v : __expf(v) - 1.0f;
                }
            }
            __syncthreads();                          // As reused next tile
        }
        return;
    }

    // ---------- fused main path ----------
    const int base = blockIdx.x * MNPB;
    if (t < 256) {                                    // stage xb rows into As[:, 0..127]
        int row = t >> 4, ch = t & 15;
        int grow = base + row; if (grow > N - 1) grow = N - 1;
        *(uint4*)(As + row * GAST + ch * 8) =
            *(const uint4*)(xb + (size_t)grow * 128 + ch * 8);
    }

    // degs + prefix over the block's 16 nodes (every wave redundantly, no barrier)
    int dg16 = 0;
    if (lane < 16 && base + lane < N) dg16 = deg[base + lane];
    int incl = dg16;
#pragma unroll
    for (int off = 1; off < 16; off <<= 1) {
        int v = __shfl_up(incl, off, 64);
        if (lane >= off) incl += v;
    }
    const int blk_s = blkoff[blockIdx.x * 2];         // blkoff is per-8-nodes
    const uint4* x4 = (const uint4*)xb;

#pragma unroll 1
    for (int half = 0; half < 2; ++half) {            // 2 sequential node-gathers per wave
        const int j = wv + half * 8;                  // local row handled this pass
        const int d = __shfl(dg16, j, 64);
        const int s = blk_s + __shfl(incl, j, 64) - d;
        const bool valid = (base + j < N);

        int idx = 0;
        if (valid && lane < d) idx = src[s + lane];   // one coalesced shot, d <= 32

        int r0 = __shfl(idx, p, 64),      r1 = __shfl(idx, p + 4, 64);
        int r2 = __shfl(idx, p + 8, 64),  r3 = __shfl(idx, p + 12, 64);
        uint4 v0 = x4[(size_t)r0 * 16 + c], v1 = x4[(size_t)r1 * 16 + c];
        uint4 v2 = x4[(size_t)r2 * 16 + c], v3 = x4[(size_t)r3 * 16 + c];
        uint4 v4, v5, v6, v7;
        const bool two = (d > 16);
        if (two) {                                    // second batch issued before any accumulate
            int e = 16 + p;
            int r4 = __shfl(idx, e, 64),      r5 = __shfl(idx, e + 4, 64);
            int r6 = __shfl(idx, e + 8, 64),  r7 = __shfl(idx, e + 12, 64);
            v4 = x4[(size_t)r4 * 16 + c]; v5 = x4[(size_t)r5 * 16 + c];
            v6 = x4[(size_t)r6 * 16 + c]; v7 = x4[(size_t)r7 * 16 + c];
        }
        float a[8] = {0,0,0,0,0,0,0,0};
        float b[8] = {0,0,0,0,0,0,0,0};
        acc8(a, v0, (p      < d) ? ~0u : 0u);
        acc8(b, v1, (p + 4  < d) ? ~0u : 0u);
        acc8(a, v2, (p + 8  < d) ? ~0u : 0u);
        acc8(b, v3, (p + 12 < d) ? ~0u : 0u);
        if (two) {
            int e = 16 + p;
            acc8(a, v4, (e      < d) ? ~0u : 0u);
            acc8(b, v5, (e + 4  < d) ? ~0u : 0u);
            acc8(a, v6, (e + 8  < d) ? ~0u : 0u);
            acc8(b, v7, (e + 12 < d) ? ~0u : 0u);
        }
#pragma unroll
        for (int i = 0; i < 8; ++i) a[i] += b[i];
#pragma unroll
        for (int i = 0; i < 8; ++i) {
            a[i] += __shfl_xor(a[i], 16, 64);
            a[i] += __shfl_xor(a[i], 32, 64);
        }
        if (p == 0 && valid) {                        // mean row -> A-panel M slot (bf16,
            float inv = (d > 0) ? 1.0f / (float)d : 0.0f;   // identical rounding to Mm path)
            uint4 u;
            u.x = (unsigned)f2bf(a[0]*inv) | ((unsigned)f2bf(a[1]*inv) << 16);
            u.y = (unsigned)f2bf(a[2]*inv) | ((unsigned)f2bf(a[3]*inv) << 16);
            u.z = (unsigned)f2bf(a[4]*inv) | ((unsigned)f2bf(a[5]*inv) << 16);
            u.w = (unsigned)f2bf(a[6]*inv) | ((unsigned)f2bf(a[7]*inv) << 16);
            *(uint4*)(As + j * GAST + 128 + c * 8) = u;
        }
    }

    const bf16x8* VB = (const bf16x8*)Vp;
    bf16x8 b0 = VB[(wv * 8) * 64 + lane];             // B prefetch before the barrier
    __syncthreads();

    f32x4 acc = (f32x4){0.f, 0.f, 0.f, 0.f};
#pragma unroll
    for (int s2 = 0; s2 < 8; ++s2) {
        int sn = (s2 + 1) & 7;                        // branchless prefetch
        bf16x8 n0 = VB[(wv * 8 + sn) * 64 + lane];
        bf16x8 a0 = *(const bf16x8*)(As + c * GAST + s2 * 32 + p * 8);
        acc = __builtin_amdgcn_mfma_f32_16x16x32_bf16(a0, b0, acc, 0, 0, 0);
        b0 = n0;
    }

    // epilogue: + bias, ELU, store. C/D: col=lane&15, row=p*4+reg. deg==0 rows are
    // owned by repair blocks in this same launch -> must skip here (disjoint writes).
    const int col = wv * 16 + c;
    const float bv = bias[col];
#pragma unroll
    for (int reg = 0; reg < 4; ++reg) {
        int lrow = p * 4 + reg;
        int grow = base + lrow;
        int rdeg = __shfl(dg16, lrow, 64);
        if (grow < N && rdeg > 0) {
            float v = acc[reg] + bv;
            out[(size_t)grow * 128 + col] = (v > 0.f) ? v : __expf(v) - 1.0f;
        }
    }
}

extern "C" void kernel_launch(void* const* d_in, const int* in_sizes, int n_in,
                              void* d_out, int out_size, void* d_ws, size_t ws_size,
                              hipStream_t stream) {
    const float* x  = (const float*)d_in[0];
    const float* Wg = (const float*)d_in[1];
    const float* Wl = (const float*)d_in[2];
    const float* Ws = (const float*)d_in[3];
    const float* b  = (const float*)d_in[4];
    const int*   src = (const int*)d_in[5];
    const int*   dst = (const int*)d_in[6];
    const int*   deg = (const int*)d_in[7];
    const int E = in_sizes[5];
    const int N = in_sizes[7];
    float* out = (float*)d_out;

    unsigned short* Vp     = (unsigned short*)d_ws;               // 64 KB
    unsigned short* Vpg    = (unsigned short*)((char*)d_ws + 65536);      // 32 KB
    int*            blkoff = (int*)((char*)d_ws + 98304);         // 32 KB reserved
    unsigned short* xb     = (unsigned short*)((char*)d_ws + 131072);     // 12.8 MB

    const int nblk_g = (N + GNPB - 1) / GNPB;      // 6250 (blkoff entries, per-8-nodes)
    const int noffb  = (nblk_g + 255) / 256;       // 25
    const int total8 = N * 16;
    const int nconv  = (total8 + 255) / 256;       // 3125
    const int ngemm  = (N + MNPB - 1) / MNPB;      // 3125
    const int ndeg   = (N + DFRNG - 1) / DFRNG;    // 98

    prep<<<dim3(VP_BLOCKS + VPG_BLOCKS + noffb + nconv), dim3(256), 0, stream>>>(
        x, Wg, Wl, Ws, dst, Vp, Vpg, xb, blkoff, total8, nblk_g, noffb, E);
    ggemm<<<dim3(ngemm + ndeg), dim3(512), 0, stream>>>(
        xb, src, deg, blkoff, Vp, Vpg, b, out, N, ngemm);
}

// Round 10
// 136.143 us; speedup vs baseline: 1.0261x; 1.0261x over previous
//
#include <hip/hip_runtime.h>
#include <cstdint>
#include <cstddef>

#define GNPB 8        // blkoff granularity (edge offset every 8 nodes)
#define MNPB 16       // rows per fused block (= gemm tile rows)
#define GAST 264      // LDS A row stride in elems (528 B) — breaks 512B-stride banks
#define DFRNG 512     // nodes scanned per repair block
#define VP_BLOCKS 16  // prep blocks packing Vp (4096 threads, K=256)
#define VPG_BLOCKS 8  // prep blocks packing Vpg (2048 threads, K=128, Wg only)

typedef __attribute__((ext_vector_type(8))) short bf16x8;
typedef __attribute__((ext_vector_type(4))) float f32x4;

static __device__ __forceinline__ unsigned short f2bf(float f) {
    unsigned int u = __builtin_bit_cast(unsigned int, f);
    u += 0x7fffu + ((u >> 16) & 1u);
    return (unsigned short)(u >> 16);
}
static __device__ __forceinline__ float bfhi(unsigned int u) { return __builtin_bit_cast(float, u & 0xFFFF0000u); }
static __device__ __forceinline__ float bflo(unsigned int u) { return __builtin_bit_cast(float, u << 16); }
// unmasked bf16x8 accumulate — invalid slots point at the zero row (adds +0.0 exactly)
static __device__ __forceinline__ void add8(float* a, const uint4& v) {
    a[0] += bflo(v.x); a[1] += bfhi(v.x); a[2] += bflo(v.y); a[3] += bfhi(v.y);
    a[4] += bflo(v.z); a[5] += bfhi(v.z); a[6] += bflo(v.w); a[7] += bfhi(v.w);
}

// ---------------- Prep: Vp/Vpg pack, xb = bf16(x) (+ zero row N), blkoff ----------------
// Vp layout: element ((g*8 + s)*64 + lane)*8 + j = B1[g*16 + (lane&15)][s*32 + (lane>>4)*8 + j]
// (B1 = [Wg+Ws | Wl], K=256). Vpg: same pattern, 4 k-steps, Wg only (K=128).
__global__ __launch_bounds__(256)
void prep(const float* __restrict__ x, const float* __restrict__ Wg,
          const float* __restrict__ Wl, const float* __restrict__ Ws,
          const int* __restrict__ dst,
          unsigned short* __restrict__ Vp, unsigned short* __restrict__ Vpg,
          unsigned short* __restrict__ xb, int* __restrict__ blkoff,
          int total8, int nblk_g, int noffb, int E) {
    const int bx = blockIdx.x, t = threadIdx.x;
    if (bx < VP_BLOCKS) {
        int gid = bx * 256 + t;
        if (gid < 4096) {
            int l = gid & 63, srow = (gid >> 6) & 7, g = gid >> 9;
            int o = g * 16 + (l & 15);
            int k = srow * 32 + (l >> 4) * 8;
            uint4 u;
            if (k < 128) {                     // first K-segment: W1 = Wg + Ws
                const float* pg = Wg + o * 128 + k;
                const float* ps = Ws + o * 128 + k;
                u.x = (unsigned)f2bf(pg[0]+ps[0]) | ((unsigned)f2bf(pg[1]+ps[1]) << 16);
                u.y = (unsigned)f2bf(pg[2]+ps[2]) | ((unsigned)f2bf(pg[3]+ps[3]) << 16);
                u.z = (unsigned)f2bf(pg[4]+ps[4]) | ((unsigned)f2bf(pg[5]+ps[5]) << 16);
                u.w = (unsigned)f2bf(pg[6]+ps[6]) | ((unsigned)f2bf(pg[7]+ps[7]) << 16);
            } else {                           // second K-segment: Wl
                const float* pl = Wl + o * 128 + (k - 128);
                u.x = (unsigned)f2bf(pl[0]) | ((unsigned)f2bf(pl[1]) << 16);
                u.y = (unsigned)f2bf(pl[2]) | ((unsigned)f2bf(pl[3]) << 16);
                u.z = (unsigned)f2bf(pl[4]) | ((unsigned)f2bf(pl[5]) << 16);
                u.w = (unsigned)f2bf(pl[6]) | ((unsigned)f2bf(pl[7]) << 16);
            }
            ((uint4*)Vp)[gid] = u;
        }
    } else if (bx < VP_BLOCKS + VPG_BLOCKS) {
        int gid = (bx - VP_BLOCKS) * 256 + t;  // 2048 entries: Wg-only panel, K=128
        if (gid < 2048) {
            int l = gid & 63, s = (gid >> 6) & 3, g = gid >> 8;
            int o = g * 16 + (l & 15);
            int k = s * 32 + (l >> 4) * 8;
            const float* p = Wg + o * 128 + k;
            uint4 u;
            u.x = (unsigned)f2bf(p[0]) | ((unsigned)f2bf(p[1]) << 16);
            u.y = (unsigned)f2bf(p[2]) | ((unsigned)f2bf(p[3]) << 16);
            u.z = (unsigned)f2bf(p[4]) | ((unsigned)f2bf(p[5]) << 16);
            u.w = (unsigned)f2bf(p[6]) | ((unsigned)f2bf(p[7]) << 16);
            ((uint4*)Vpg)[gid] = u;
        }
    } else if (bx < VP_BLOCKS + VPG_BLOCKS + noffb) {
        int b = (bx - VP_BLOCKS - VPG_BLOCKS) * 256 + t;
        if (b < nblk_g) {
            int target = b * GNPB;
            int lo = 0, hi = E;
            while (lo < hi) { int mid = (lo + hi) >> 1; if (dst[mid] < target) lo = mid + 1; else hi = mid; }
            blkoff[b] = lo;
        }
    } else {
        int gid = (bx - VP_BLOCKS - VPG_BLOCKS - noffb) * 256 + t;
        if (gid < total8) {
            const float4* px = (const float4*)x + (size_t)gid * 2;
            float4 a = px[0], bq = px[1];
            uint4 u;
            u.x = (unsigned)f2bf(a.x)  | ((unsigned)f2bf(a.y)  << 16);
            u.y = (unsigned)f2bf(a.z)  | ((unsigned)f2bf(a.w)  << 16);
            u.z = (unsigned)f2bf(bq.x) | ((unsigned)f2bf(bq.y) << 16);
            u.w = (unsigned)f2bf(bq.z) | ((unsigned)f2bf(bq.w) << 16);
            ((uint4*)xb)[gid] = u;
        } else if (gid < total8 + 16) {
            ((uint4*)xb)[gid] = (uint4){0u, 0u, 0u, 0u};   // zero row at index N
        }
    }
}

// ---------------- Fused gather + GEMM + repair (one dispatch) ----------------
// Repair blocks FIRST (blockIdx < ndeg) so they overlap main work instead of
// extending the tail. Main blocks: 512 threads / 8 waves / 16 nodes. Gather:
// 2 nodes per wave with ALL 16 row-loads issued before any accumulate (one
// latency chain, not two — R9's serial halves were the stall). Invalid slots
// gather the zero row xb[N] -> unmasked accumulate (saves ~30% of gather VALU).
// GEMM: one col-group per wave, 8 MFMA, B streamed from Vp. deg==0 rows skipped
// (repair owns them; disjoint writes).
__global__ __launch_bounds__(512, 4)
void ggemm(const unsigned short* __restrict__ xb, const int* __restrict__ src,
           const int* __restrict__ deg, const int* __restrict__ blkoff,
           const unsigned short* __restrict__ Vp, const unsigned short* __restrict__ Vpg,
           const float* __restrict__ bias, float* __restrict__ out, int N, int ndeg) {
    __shared__ __align__(16) unsigned short As[MNPB * GAST];
    const int t = threadIdx.x, wv = t >> 6, lane = t & 63;
    const int c = lane & 15, p = lane >> 4;          // p doubles as the C/D quad index

    if (blockIdx.x < ndeg) {
        // ---------- repair path ----------
        __shared__ int nds[DFRNG];
        __shared__ int ncnt;
        const int rb = blockIdx.x * DFRNG;
        if (t == 0) ncnt = 0;
        __syncthreads();
        {
            int n = rb + t;
            if (n < N && deg[n] == 0) nds[atomicAdd(&ncnt, 1)] = n;
        }
        __syncthreads();
        const int cnt = ncnt;
        if (cnt == 0) return;
        const bf16x8* VB = (const bf16x8*)Vpg;
        const int col = wv * 16 + c;
        const float bv = bias[col];
        for (int base = 0; base < cnt; base += 16) {
            if (t < 256) {                            // stage 16 compacted rows
                int row = t >> 4, ch = t & 15;
                int i = base + row; if (i > cnt - 1) i = cnt - 1;
                int node = nds[i];
                *(uint4*)(As + row * GAST + ch * 8) =
                    *(const uint4*)(xb + (size_t)node * 128 + ch * 8);
            }
            bf16x8 b0 = VB[(wv * 4) * 64 + lane];
            __syncthreads();
            f32x4 acc = (f32x4){0.f, 0.f, 0.f, 0.f};
#pragma unroll
            for (int s2 = 0; s2 < 4; ++s2) {
                int sn = (s2 + 1) & 3;
                bf16x8 n0 = VB[(wv * 4 + sn) * 64 + lane];
                bf16x8 a0 = *(const bf16x8*)(As + c * GAST + s2 * 32 + p * 8);
                acc = __builtin_amdgcn_mfma_f32_16x16x32_bf16(a0, b0, acc, 0, 0, 0);
                b0 = n0;
            }
#pragma unroll
            for (int reg = 0; reg < 4; ++reg) {
                int i = base + p * 4 + reg;
                if (i < cnt) {
                    int n = nds[i];
                    float v = acc[reg] + bv;
                    out[(size_t)n * 128 + col] = (v > 0.f) ? v : __expf(v) - 1.0f;
                }
            }
            __syncthreads();                          // As reused next tile
        }
        return;
    }

    // ---------- fused main path ----------
    const int bid = blockIdx.x - ndeg;
    const int base = bid * MNPB;
    if (t < 256) {                                    // stage xb rows into As[:, 0..127]
        int row = t >> 4, ch = t & 15;
        int grow = base + row; if (grow > N - 1) grow = N - 1;
        *(uint4*)(As + row * GAST + ch * 8) =
            *(const uint4*)(xb + (size_t)grow * 128 + ch * 8);
    }

    // degs + prefix over the block's 16 nodes (every wave redundantly, no barrier)
    int dg16 = 0;
    if (lane < 16 && base + lane < N) dg16 = deg[base + lane];
    int incl = dg16;
#pragma unroll
    for (int off = 1; off < 16; off <<= 1) {
        int v = __shfl_up(incl, off, 64);
        if (lane >= off) incl += v;
    }
    const int blk_s = blkoff[bid * 2];                // blkoff is per-8-nodes
    const uint4* x4 = (const uint4*)xb;

    // -- both nodes' src loads, then ALL row loads in flight, then accumulate --
    const int jA = wv, jB = wv + 8;
    const int dA = __shfl(dg16, jA, 64), dB = __shfl(dg16, jB, 64);
    const int sA = blk_s + __shfl(incl, jA, 64) - dA;
    const int sB = blk_s + __shfl(incl, jB, 64) - dB;
    const bool vA = (base + jA < N), vB = (base + jB < N);

    int idxA = N, idxB = N;                           // default: zero row
    if (vA && lane < dA) idxA = src[sA + lane];
    if (vB && lane < dB) idxB = src[sB + lane];

    int a0i = __shfl(idxA, p, 64),      a1i = __shfl(idxA, p + 4, 64);
    int a2i = __shfl(idxA, p + 8, 64),  a3i = __shfl(idxA, p + 12, 64);
    uint4 vA0 = x4[(size_t)a0i * 16 + c], vA1 = x4[(size_t)a1i * 16 + c];
    uint4 vA2 = x4[(size_t)a2i * 16 + c], vA3 = x4[(size_t)a3i * 16 + c];
    uint4 vA4, vA5, vA6, vA7;
    const bool twoA = (dA > 16);
    if (twoA) {
        int e = 16 + p;
        int a4i = __shfl(idxA, e, 64),      a5i = __shfl(idxA, e + 4, 64);
        int a6i = __shfl(idxA, e + 8, 64),  a7i = __shfl(idxA, e + 12, 64);
        vA4 = x4[(size_t)a4i * 16 + c]; vA5 = x4[(size_t)a5i * 16 + c];
        vA6 = x4[(size_t)a6i * 16 + c]; vA7 = x4[(size_t)a7i * 16 + c];
    }
    int b0i = __shfl(idxB, p, 64),      b1i = __shfl(idxB, p + 4, 64);
    int b2i = __shfl(idxB, p + 8, 64),  b3i = __shfl(idxB, p + 12, 64);
    uint4 vB0 = x4[(size_t)b0i * 16 + c], vB1 = x4[(size_t)b1i * 16 + c];
    uint4 vB2 = x4[(size_t)b2i * 16 + c], vB3 = x4[(size_t)b3i * 16 + c];
    uint4 vB4, vB5, vB6, vB7;
    const bool twoB = (dB > 16);
    if (twoB) {
        int e = 16 + p;
        int b4i = __shfl(idxB, e, 64),      b5i = __shfl(idxB, e + 4, 64);
        int b6i = __shfl(idxB, e + 8, 64),  b7i = __shfl(idxB, e + 12, 64);
        vB4 = x4[(size_t)b4i * 16 + c]; vB5 = x4[(size_t)b5i * 16 + c];
        vB6 = x4[(size_t)b6i * 16 + c]; vB7 = x4[(size_t)b7i * 16 + c];
    }

    {   // accumulate node A (same add order as the proven kernel -> same rounding)
        float a[8] = {0,0,0,0,0,0,0,0};
        float b[8] = {0,0,0,0,0,0,0,0};
        add8(a, vA0); add8(b, vA1); add8(a, vA2); add8(b, vA3);
        if (twoA) { add8(a, vA4); add8(b, vA5); add8(a, vA6); add8(b, vA7); }
#pragma unroll
        for (int i = 0; i < 8; ++i) a[i] += b[i];
#pragma unroll
        for (int i = 0; i < 8; ++i) {
            a[i] += __shfl_xor(a[i], 16, 64);
            a[i] += __shfl_xor(a[i], 32, 64);
        }
        if (p == 0 && vA) {
            float inv = (dA > 0) ? 1.0f / (float)dA : 0.0f;
            uint4 u;
            u.x = (unsigned)f2bf(a[0]*inv) | ((unsigned)f2bf(a[1]*inv) << 16);
            u.y = (unsigned)f2bf(a[2]*inv) | ((unsigned)f2bf(a[3]*inv) << 16);
            u.z = (unsigned)f2bf(a[4]*inv) | ((unsigned)f2bf(a[5]*inv) << 16);
            u.w = (unsigned)f2bf(a[6]*inv) | ((unsigned)f2bf(a[7]*inv) << 16);
            *(uint4*)(As + jA * GAST + 128 + c * 8) = u;
        }
    }
    {   // accumulate node B
        float a[8] = {0,0,0,0,0,0,0,0};
        float b[8] = {0,0,0,0,0,0,0,0};
        add8(a, vB0); add8(b, vB1); add8(a, vB2); add8(b, vB3);
        if (twoB) { add8(a, vB4); add8(b, vB5); add8(a, vB6); add8(b, vB7); }
#pragma unroll
        for (int i = 0; i < 8; ++i) a[i] += b[i];
#pragma unroll
        for (int i = 0; i < 8; ++i) {
            a[i] += __shfl_xor(a[i], 16, 64);
            a[i] += __shfl_xor(a[i], 32, 64);
        }
        if (p == 0 && vB) {
            float inv = (dB > 0) ? 1.0f / (float)dB : 0.0f;
            uint4 u;
            u.x = (unsigned)f2bf(a[0]*inv) | ((unsigned)f2bf(a[1]*inv) << 16);
            u.y = (unsigned)f2bf(a[2]*inv) | ((unsigned)f2bf(a[3]*inv) << 16);
            u.z = (unsigned)f2bf(a[4]*inv) | ((unsigned)f2bf(a[5]*inv) << 16);
            u.w = (unsigned)f2bf(a[6]*inv) | ((unsigned)f2bf(a[7]*inv) << 16);
            *(uint4*)(As + jB * GAST + 128 + c * 8) = u;
        }
    }

    const bf16x8* VB = (const bf16x8*)Vp;
    bf16x8 b0 = VB[(wv * 8) * 64 + lane];             // B prefetch before the barrier
    __syncthreads();

    f32x4 acc = (f32x4){0.f, 0.f, 0.f, 0.f};
#pragma unroll
    for (int s2 = 0; s2 < 8; ++s2) {
        int sn = (s2 + 1) & 7;                        // branchless prefetch
        bf16x8 n0 = VB[(wv * 8 + sn) * 64 + lane];
        bf16x8 a0 = *(const bf16x8*)(As + c * GAST + s2 * 32 + p * 8);
        acc = __builtin_amdgcn_mfma_f32_16x16x32_bf16(a0, b0, acc, 0, 0, 0);
        b0 = n0;
    }

    // epilogue: + bias, ELU, store. C/D: col=lane&15, row=p*4+reg. deg==0 rows are
    // owned by repair blocks in this same launch -> must skip here (disjoint writes).
    const int col = wv * 16 + c;
    const float bv = bias[col];
#pragma unroll
    for (int reg = 0; reg < 4; ++reg) {
        int lrow = p * 4 + reg;
        int grow = base + lrow;
        int rdeg = __shfl(dg16, lrow, 64);
        if (grow < N && rdeg > 0) {
            float v = acc[reg] + bv;
            out[(size_t)grow * 128 + col] = (v > 0.f) ? v : __expf(v) - 1.0f;
        }
    }
}

extern "C" void kernel_launch(void* const* d_in, const int* in_sizes, int n_in,
                              void* d_out, int out_size, void* d_ws, size_t ws_size,
                              hipStream_t stream) {
    const float* x  = (const float*)d_in[0];
    const float* Wg = (const float*)d_in[1];
    const float* Wl = (const float*)d_in[2];
    const float* Ws = (const float*)d_in[3];
    const float* b  = (const float*)d_in[4];
    const int*   src = (const int*)d_in[5];
    const int*   dst = (const int*)d_in[6];
    const int*   deg = (const int*)d_in[7];
    const int E = in_sizes[5];
    const int N = in_sizes[7];
    float* out = (float*)d_out;

    unsigned short* Vp     = (unsigned short*)d_ws;               // 64 KB
    unsigned short* Vpg    = (unsigned short*)((char*)d_ws + 65536);      // 32 KB
    int*            blkoff = (int*)((char*)d_ws + 98304);         // 32 KB reserved
    unsigned short* xb     = (unsigned short*)((char*)d_ws + 131072);     // 12.8 MB + zero row

    const int nblk_g = (N + GNPB - 1) / GNPB;      // 6250 (blkoff entries, per-8-nodes)
    const int noffb  = (nblk_g + 255) / 256;       // 25
    const int total8 = N * 16;
    const int nconv  = (total8 + 16 + 255) / 256;  // 3126 (+ zero row)
    const int ngemm  = (N + MNPB - 1) / MNPB;      // 3125
    const int ndeg   = (N + DFRNG - 1) / DFRNG;    // 98

    prep<<<dim3(VP_BLOCKS + VPG_BLOCKS + noffb + nconv), dim3(256), 0, stream>>>(
        x, Wg, Wl, Ws, dst, Vp, Vpg, xb, blkoff, total8, nblk_g, noffb, E);
    ggemm<<<dim3(ngemm + ndeg), dim3(512), 0, stream>>>(
        xb, src, deg, blkoff, Vp, Vpg, b, out, N, ndeg);
}

// Round 11
// 135.479 us; speedup vs baseline: 1.0312x; 1.0049x over previous
//
#include <hip/hip_runtime.h>
#include <cstdint>
#include <cstddef>

#define GNPB 8        // blkoff granularity (edge offset every 8 nodes)
#define MNPB 16       // rows per fused block (= gemm tile rows)
#define GAST 264      // LDS A row stride in elems (528 B) — breaks 512B-stride banks
#define DFRNG 512     // nodes scanned per repair block
#define VP_BLOCKS 16  // prep blocks packing Vp (4096 threads, K=256)
#define VPG_BLOCKS 8  // prep blocks packing Vpg (2048 threads, K=128, Wg only)

typedef __attribute__((ext_vector_type(8))) short bf16x8;
typedef __attribute__((ext_vector_type(4))) float f32x4;

static __device__ __forceinline__ unsigned short f2bf(float f) {
    unsigned int u = __builtin_bit_cast(unsigned int, f);
    u += 0x7fffu + ((u >> 16) & 1u);
    return (unsigned short)(u >> 16);
}
static __device__ __forceinline__ float bfhi(unsigned int u) { return __builtin_bit_cast(float, u & 0xFFFF0000u); }
static __device__ __forceinline__ float bflo(unsigned int u) { return __builtin_bit_cast(float, u << 16); }
// unmasked bf16x8 accumulate — invalid slots point at the zero row (adds +0.0 exactly)
static __device__ __forceinline__ void add8(float* a, const uint4& v) {
    a[0] += bflo(v.x); a[1] += bfhi(v.x); a[2] += bflo(v.y); a[3] += bfhi(v.y);
    a[4] += bflo(v.z); a[5] += bfhi(v.z); a[6] += bflo(v.w); a[7] += bfhi(v.w);
}

// ---------------- Prep: Vp/Vpg pack, xb = bf16(x) (+ zero row N), blkoff ----------------
// Vp layout: element ((g*8 + s)*64 + lane)*8 + j = B1[g*16 + (lane&15)][s*32 + (lane>>4)*8 + j]
// (B1 = [Wg+Ws | Wl], K=256). Vpg: same pattern, 4 k-steps, Wg only (K=128).
__global__ __launch_bounds__(256)
void prep(const float* __restrict__ x, const float* __restrict__ Wg,
          const float* __restrict__ Wl, const float* __restrict__ Ws,
          const int* __restrict__ dst,
          unsigned short* __restrict__ Vp, unsigned short* __restrict__ Vpg,
          unsigned short* __restrict__ xb, int* __restrict__ blkoff,
          int total8, int nblk_g, int noffb, int E) {
    const int bx = blockIdx.x, t = threadIdx.x;
    if (bx < VP_BLOCKS) {
        int gid = bx * 256 + t;
        if (gid < 4096) {
            int l = gid & 63, srow = (gid >> 6) & 7, g = gid >> 9;
            int o = g * 16 + (l & 15);
            int k = srow * 32 + (l >> 4) * 8;
            uint4 u;
            if (k < 128) {                     // first K-segment: W1 = Wg + Ws
                const float* pg = Wg + o * 128 + k;
                const float* ps = Ws + o * 128 + k;
                u.x = (unsigned)f2bf(pg[0]+ps[0]) | ((unsigned)f2bf(pg[1]+ps[1]) << 16);
                u.y = (unsigned)f2bf(pg[2]+ps[2]) | ((unsigned)f2bf(pg[3]+ps[3]) << 16);
                u.z = (unsigned)f2bf(pg[4]+ps[4]) | ((unsigned)f2bf(pg[5]+ps[5]) << 16);
                u.w = (unsigned)f2bf(pg[6]+ps[6]) | ((unsigned)f2bf(pg[7]+ps[7]) << 16);
            } else {                           // second K-segment: Wl
                const float* pl = Wl + o * 128 + (k - 128);
                u.x = (unsigned)f2bf(pl[0]) | ((unsigned)f2bf(pl[1]) << 16);
                u.y = (unsigned)f2bf(pl[2]) | ((unsigned)f2bf(pl[3]) << 16);
                u.z = (unsigned)f2bf(pl[4]) | ((unsigned)f2bf(pl[5]) << 16);
                u.w = (unsigned)f2bf(pl[6]) | ((unsigned)f2bf(pl[7]) << 16);
            }
            ((uint4*)Vp)[gid] = u;
        }
    } else if (bx < VP_BLOCKS + VPG_BLOCKS) {
        int gid = (bx - VP_BLOCKS) * 256 + t;  // 2048 entries: Wg-only panel, K=128
        if (gid < 2048) {
            int l = gid & 63, s = (gid >> 6) & 3, g = gid >> 8;
            int o = g * 16 + (l & 15);
            int k = s * 32 + (l >> 4) * 8;
            const float* p = Wg + o * 128 + k;
            uint4 u;
            u.x = (unsigned)f2bf(p[0]) | ((unsigned)f2bf(p[1]) << 16);
            u.y = (unsigned)f2bf(p[2]) | ((unsigned)f2bf(p[3]) << 16);
            u.z = (unsigned)f2bf(p[4]) | ((unsigned)f2bf(p[5]) << 16);
            u.w = (unsigned)f2bf(p[6]) | ((unsigned)f2bf(p[7]) << 16);
            ((uint4*)Vpg)[gid] = u;
        }
    } else if (bx < VP_BLOCKS + VPG_BLOCKS + noffb) {
        int b = (bx - VP_BLOCKS - VPG_BLOCKS) * 256 + t;
        if (b < nblk_g) {
            int target = b * GNPB;
            int lo = 0, hi = E;
            while (lo < hi) { int mid = (lo + hi) >> 1; if (dst[mid] < target) lo = mid + 1; else hi = mid; }
            blkoff[b] = lo;
        }
    } else {
        int gid = (bx - VP_BLOCKS - VPG_BLOCKS - noffb) * 256 + t;
        if (gid < total8) {
            const float4* px = (const float4*)x + (size_t)gid * 2;
            float4 a = px[0], bq = px[1];
            uint4 u;
            u.x = (unsigned)f2bf(a.x)  | ((unsigned)f2bf(a.y)  << 16);
            u.y = (unsigned)f2bf(a.z)  | ((unsigned)f2bf(a.w)  << 16);
            u.z = (unsigned)f2bf(bq.x) | ((unsigned)f2bf(bq.y) << 16);
            u.w = (unsigned)f2bf(bq.z) | ((unsigned)f2bf(bq.w) << 16);
            ((uint4*)xb)[gid] = u;
        } else if (gid < total8 + 16) {
            ((uint4*)xb)[gid] = (uint4){0u, 0u, 0u, 0u};   // zero row at index N
        }
    }
}

// ---------------- Fused gather + GEMM + repair (one dispatch) ----------------
// Repair blocks FIRST (blockIdx < ndeg) so they overlap main work instead of
// extending the tail. Main blocks: 512 threads / 8 waves / 16 nodes. Gather:
// 2 nodes per wave, ALL 16 row-loads issued, then sched_barrier(0) pins the
// cluster (R10 evidence: without it the compiler re-serialized — VGPR stayed 48,
// i.e. loads sunk to their uses; the barrier forces 16 in flight -> one latency
// exposure per wave). Invalid slots gather the zero row xb[N] -> unmasked adds.
// GEMM: one col-group per wave, 8 MFMA, B streamed from Vp. deg==0 rows skipped
// (repair owns them; disjoint writes).
__global__ __launch_bounds__(512, 4)
void ggemm(const unsigned short* __restrict__ xb, const int* __restrict__ src,
           const int* __restrict__ deg, const int* __restrict__ blkoff,
           const unsigned short* __restrict__ Vp, const unsigned short* __restrict__ Vpg,
           const float* __restrict__ bias, float* __restrict__ out, int N, int ndeg) {
    __shared__ __align__(16) unsigned short As[MNPB * GAST];
    const int t = threadIdx.x, wv = t >> 6, lane = t & 63;
    const int c = lane & 15, p = lane >> 4;          // p doubles as the C/D quad index

    if (blockIdx.x < ndeg) {
        // ---------- repair path ----------
        __shared__ int nds[DFRNG];
        __shared__ int ncnt;
        const int rb = blockIdx.x * DFRNG;
        if (t == 0) ncnt = 0;
        __syncthreads();
        {
            int n = rb + t;
            if (n < N && deg[n] == 0) nds[atomicAdd(&ncnt, 1)] = n;
        }
        __syncthreads();
        const int cnt = ncnt;
        if (cnt == 0) return;
        const bf16x8* VB = (const bf16x8*)Vpg;
        const int col = wv * 16 + c;
        const float bv = bias[col];
        for (int base = 0; base < cnt; base += 16) {
            if (t < 256) {                            // stage 16 compacted rows
                int row = t >> 4, ch = t & 15;
                int i = base + row; if (i > cnt - 1) i = cnt - 1;
                int node = nds[i];
                *(uint4*)(As + row * GAST + ch * 8) =
                    *(const uint4*)(xb + (size_t)node * 128 + ch * 8);
            }
            bf16x8 b0 = VB[(wv * 4) * 64 + lane];
            __syncthreads();
            f32x4 acc = (f32x4){0.f, 0.f, 0.f, 0.f};
#pragma unroll
            for (int s2 = 0; s2 < 4; ++s2) {
                int sn = (s2 + 1) & 3;
                bf16x8 n0 = VB[(wv * 4 + sn) * 64 + lane];
                bf16x8 a0 = *(const bf16x8*)(As + c * GAST + s2 * 32 + p * 8);
                acc = __builtin_amdgcn_mfma_f32_16x16x32_bf16(a0, b0, acc, 0, 0, 0);
                b0 = n0;
            }
#pragma unroll
            for (int reg = 0; reg < 4; ++reg) {
                int i = base + p * 4 + reg;
                if (i < cnt) {
                    int n = nds[i];
                    float v = acc[reg] + bv;
                    out[(size_t)n * 128 + col] = (v > 0.f) ? v : __expf(v) - 1.0f;
                }
            }
            __syncthreads();                          // As reused next tile
        }
        return;
    }

    // ---------- fused main path ----------
    const int bid = blockIdx.x - ndeg;
    const int base = bid * MNPB;
    if (t < 256) {                                    // stage xb rows into As[:, 0..127]
        int row = t >> 4, ch = t & 15;
        int grow = base + row; if (grow > N - 1) grow = N - 1;
        *(uint4*)(As + row * GAST + ch * 8) =
            *(const uint4*)(xb + (size_t)grow * 128 + ch * 8);
    }

    // degs + prefix over the block's 16 nodes (every wave redundantly, no barrier)
    int dg16 = 0;
    if (lane < 16 && base + lane < N) dg16 = deg[base + lane];
    int incl = dg16;
#pragma unroll
    for (int off = 1; off < 16; off <<= 1) {
        int v = __shfl_up(incl, off, 64);
        if (lane >= off) incl += v;
    }
    const int blk_s = blkoff[bid * 2];                // blkoff is per-8-nodes
    const uint4* x4 = (const uint4*)xb;

    // -- both nodes' src loads, then ALL row loads in flight, then accumulate --
    const int jA = wv, jB = wv + 8;
    const int dA = __shfl(dg16, jA, 64), dB = __shfl(dg16, jB, 64);
    const int sA = blk_s + __shfl(incl, jA, 64) - dA;
    const int sB = blk_s + __shfl(incl, jB, 64) - dB;
    const bool vA = (base + jA < N), vB = (base + jB < N);

    int idxA = N, idxB = N;                           // default: zero row
    if (vA && lane < dA) idxA = src[sA + lane];
    if (vB && lane < dB) idxB = src[sB + lane];

    int a0i = __shfl(idxA, p, 64),      a1i = __shfl(idxA, p + 4, 64);
    int a2i = __shfl(idxA, p + 8, 64),  a3i = __shfl(idxA, p + 12, 64);
    uint4 vA0 = x4[(size_t)a0i * 16 + c], vA1 = x4[(size_t)a1i * 16 + c];
    uint4 vA2 = x4[(size_t)a2i * 16 + c], vA3 = x4[(size_t)a3i * 16 + c];
    uint4 vA4, vA5, vA6, vA7;
    const bool twoA = (dA > 16);
    if (twoA) {
        int e = 16 + p;
        int a4i = __shfl(idxA, e, 64),      a5i = __shfl(idxA, e + 4, 64);
        int a6i = __shfl(idxA, e + 8, 64),  a7i = __shfl(idxA, e + 12, 64);
        vA4 = x4[(size_t)a4i * 16 + c]; vA5 = x4[(size_t)a5i * 16 + c];
        vA6 = x4[(size_t)a6i * 16 + c]; vA7 = x4[(size_t)a7i * 16 + c];
    }
    int b0i = __shfl(idxB, p, 64),      b1i = __shfl(idxB, p + 4, 64);
    int b2i = __shfl(idxB, p + 8, 64),  b3i = __shfl(idxB, p + 12, 64);
    uint4 vB0 = x4[(size_t)b0i * 16 + c], vB1 = x4[(size_t)b1i * 16 + c];
    uint4 vB2 = x4[(size_t)b2i * 16 + c], vB3 = x4[(size_t)b3i * 16 + c];
    uint4 vB4, vB5, vB6, vB7;
    const bool twoB = (dB > 16);
    if (twoB) {
        int e = 16 + p;
        int b4i = __shfl(idxB, e, 64),      b5i = __shfl(idxB, e + 4, 64);
        int b6i = __shfl(idxB, e + 8, 64),  b7i = __shfl(idxB, e + 12, 64);
        vB4 = x4[(size_t)b4i * 16 + c]; vB5 = x4[(size_t)b5i * 16 + c];
        vB6 = x4[(size_t)b6i * 16 + c]; vB7 = x4[(size_t)b7i * 16 + c];
    }

    // Pin the issue order: nothing below may be hoisted above, no load may sink
    // below. This is what actually keeps 16 loads outstanding (rule #18/T19).
    __builtin_amdgcn_sched_barrier(0);

    {   // accumulate node A (same add order as the proven kernel -> same rounding)
        float a[8] = {0,0,0,0,0,0,0,0};
        float b[8] = {0,0,0,0,0,0,0,0};
        add8(a, vA0); add8(b, vA1); add8(a, vA2); add8(b, vA3);
        if (twoA) { add8(a, vA4); add8(b, vA5); add8(a, vA6); add8(b, vA7); }
#pragma unroll
        for (int i = 0; i < 8; ++i) a[i] += b[i];
#pragma unroll
        for (int i = 0; i < 8; ++i) {
            a[i] += __shfl_xor(a[i], 16, 64);
            a[i] += __shfl_xor(a[i], 32, 64);
        }
        if (p == 0 && vA) {
            float inv = (dA > 0) ? 1.0f / (float)dA : 0.0f;
            uint4 u;
            u.x = (unsigned)f2bf(a[0]*inv) | ((unsigned)f2bf(a[1]*inv) << 16);
            u.y = (unsigned)f2bf(a[2]*inv) | ((unsigned)f2bf(a[3]*inv) << 16);
            u.z = (unsigned)f2bf(a[4]*inv) | ((unsigned)f2bf(a[5]*inv) << 16);
            u.w = (unsigned)f2bf(a[6]*inv) | ((unsigned)f2bf(a[7]*inv) << 16);
            *(uint4*)(As + jA * GAST + 128 + c * 8) = u;
        }
    }
    {   // accumulate node B
        float a[8] = {0,0,0,0,0,0,0,0};
        float b[8] = {0,0,0,0,0,0,0,0};
        add8(a, vB0); add8(b, vB1); add8(a, vB2); add8(b, vB3);
        if (twoB) { add8(a, vB4); add8(b, vB5); add8(a, vB6); add8(b, vB7); }
#pragma unroll
        for (int i = 0; i < 8; ++i) a[i] += b[i];
#pragma unroll
        for (int i = 0; i < 8; ++i) {
            a[i] += __shfl_xor(a[i], 16, 64);
            a[i] += __shfl_xor(a[i], 32, 64);
        }
        if (p == 0 && vB) {
            float inv = (dB > 0) ? 1.0f / (float)dB : 0.0f;
            uint4 u;
            u.x = (unsigned)f2bf(a[0]*inv) | ((unsigned)f2bf(a[1]*inv) << 16);
            u.y = (unsigned)f2bf(a[2]*inv) | ((unsigned)f2bf(a[3]*inv) << 16);
            u.z = (unsigned)f2bf(a[4]*inv) | ((unsigned)f2bf(a[5]*inv) << 16);
            u.w = (unsigned)f2bf(a[6]*inv) | ((unsigned)f2bf(a[7]*inv) << 16);
            *(uint4*)(As + jB * GAST + 128 + c * 8) = u;
        }
    }

    const bf16x8* VB = (const bf16x8*)Vp;
    bf16x8 b0 = VB[(wv * 8) * 64 + lane];             // B prefetch before the barrier
    __syncthreads();

    f32x4 acc = (f32x4){0.f, 0.f, 0.f, 0.f};
#pragma unroll
    for (int s2 = 0; s2 < 8; ++s2) {
        int sn = (s2 + 1) & 7;                        // branchless prefetch
        bf16x8 n0 = VB[(wv * 8 + sn) * 64 + lane];
        bf16x8 a0 = *(const bf16x8*)(As + c * GAST + s2 * 32 + p * 8);
        acc = __builtin_amdgcn_mfma_f32_16x16x32_bf16(a0, b0, acc, 0, 0, 0);
        b0 = n0;
    }

    // epilogue: + bias, ELU, store. C/D: col=lane&15, row=p*4+reg. deg==0 rows are
    // owned by repair blocks in this same launch -> must skip here (disjoint writes).
    const int col = wv * 16 + c;
    const float bv = bias[col];
#pragma unroll
    for (int reg = 0; reg < 4; ++reg) {
        int lrow = p * 4 + reg;
        int grow = base + lrow;
        int rdeg = __shfl(dg16, lrow, 64);
        if (grow < N && rdeg > 0) {
            float v = acc[reg] + bv;
            out[(size_t)grow * 128 + col] = (v > 0.f) ? v : __expf(v) - 1.0f;
        }
    }
}

extern "C" void kernel_launch(void* const* d_in, const int* in_sizes, int n_in,
                              void* d_out, int out_size, void* d_ws, size_t ws_size,
                              hipStream_t stream) {
    const float* x  = (const float*)d_in[0];
    const float* Wg = (const float*)d_in[1];
    const float* Wl = (const float*)d_in[2];
    const float* Ws = (const float*)d_in[3];
    const float* b  = (const float*)d_in[4];
    const int*   src = (const int*)d_in[5];
    const int*   dst = (const int*)d_in[6];
    const int*   deg = (const int*)d_in[7];
    const int E = in_sizes[5];
    const int N = in_sizes[7];
    float* out = (float*)d_out;

    unsigned short* Vp     = (unsigned short*)d_ws;               // 64 KB
    unsigned short* Vpg    = (unsigned short*)((char*)d_ws + 65536);      // 32 KB
    int*            blkoff = (int*)((char*)d_ws + 98304);         // 32 KB reserved
    unsigned short* xb     = (unsigned short*)((char*)d_ws + 131072);     // 12.8 MB + zero row

    const int nblk_g = (N + GNPB - 1) / GNPB;      // 6250 (blkoff entries, per-8-nodes)
    const int noffb  = (nblk_g + 255) / 256;       // 25
    const int total8 = N * 16;
    const int nconv  = (total8 + 16 + 255) / 256;  // 3126 (+ zero row)
    const int ngemm  = (N + MNPB - 1) / MNPB;      // 3125
    const int ndeg   = (N + DFRNG - 1) / DFRNG;    // 98

    prep<<<dim3(VP_BLOCKS + VPG_BLOCKS + noffb + nconv), dim3(256), 0, stream>>>(
        x, Wg, Wl, Ws, dst, Vp, Vpg, xb, blkoff, total8, nblk_g, noffb, E);
    ggemm<<<dim3(ngemm + ndeg), dim3(512), 0, stream>>>(
        xb, src, deg, blkoff, Vp, Vpg, b, out, N, ndeg);
}